// Round 1
// baseline (1498.056 us; speedup 1.0000x reference)
//
#include <hip/hip_runtime.h>
#include <hip/hip_bf16.h>

typedef __hip_bfloat16 bf16;
typedef __attribute__((ext_vector_type(4))) float f32x4;
typedef __attribute__((ext_vector_type(8))) __bf16 bf16x8;

constexpr int kE   = 1152;
constexpr int kH   = 16;
constexpr int kHD2 = 36;
constexpr int kFF  = 4304;
constexpr int kFFP = 4352;   // padded to 34*128
constexpr int kB   = 32;
constexpr int kS   = 256;
constexpr int kT   = kB * kS;      // 8192 tokens
constexpr int kNQKV = 3 * kE;      // 3456
constexpr float kLambdaInit = 0.7778701f;   // 0.8 - 0.6*exp(-0.3*11)
constexpr float kRmsEps = 1e-6f;
constexpr float kSublnEps = 1e-5f;

__device__ inline void async_copy16(const void* gsrc, void* ldst) {
    __builtin_amdgcn_global_load_lds(
        (__attribute__((address_space(1))) void*)gsrc,
        (__attribute__((address_space(3))) void*)ldst, 16, 0, 0);
}

// ---------------- weight convert / pad ----------------
__global__ __launch_bounds__(256) void convert_pad(
    const float* __restrict__ src, bf16* __restrict__ dst,
    int N, int K, int Kpad, int total)
{
    int i = blockIdx.x * 256 + threadIdx.x;
    if (i >= total) return;
    int n = i / Kpad, k = i - n * Kpad;
    float v = (n < N && k < K) ? src[(size_t)n * K + k] : 0.f;
    dst[i] = __float2bfloat16(v);
}

__global__ __launch_bounds__(256) void prep_bias(
    const float* __restrict__ bq, const float* __restrict__ bk,
    const float* __restrict__ bv, const float* __restrict__ fb,
    float* __restrict__ bqkv, float* __restrict__ fbp)
{
    int i = blockIdx.x * 256 + threadIdx.x;
    if (i < kNQKV) {
        float v = (i < kE) ? bq[i] : (i < 2 * kE) ? bk[i - kE] : bv[i - 2 * kE];
        bqkv[i] = v;
    }
    if (i < kFFP) fbp[i] = (i < kFF) ? fb[i] : 0.f;
}

// ---------------- RMSNorm (fp32 in -> bf16 out) ----------------
__global__ __launch_bounds__(256) void rmsnorm_kernel(
    const float* __restrict__ x, const float* __restrict__ w,
    bf16* __restrict__ out, float eps)
{
    int row = blockIdx.x;
    const float* xr = x + (size_t)row * kE;
    float vals[5];
    float ss = 0.f;
    int n = 0;
    for (int j = threadIdx.x; j < kE; j += 256) {
        float v = xr[j];
        vals[n++] = v;
        ss += v * v;
    }
    for (int m = 32; m > 0; m >>= 1) ss += __shfl_xor(ss, m, 64);
    __shared__ float red[4];
    if ((threadIdx.x & 63) == 0) red[threadIdx.x >> 6] = ss;
    __syncthreads();
    float tot = red[0] + red[1] + red[2] + red[3];
    float scale = rsqrtf(tot / (float)kE + eps);
    n = 0;
    for (int j = threadIdx.x; j < kE; j += 256)
        out[(size_t)row * kE + j] = __float2bfloat16(vals[n++] * scale * w[j]);
}

// ---------------- bf16 NT GEMM, 128x128 tile, BK=32 ----------------
// A [M,K] bf16 row-major, Bw [N,K] bf16 row-major, C[M,N].
// EPI: 0 = bf16 out (+bias), 1 = gelu-tanh bf16 out (+bias), 2 = fp32 out (+bias+add)
template <int EPI>
__global__ __launch_bounds__(256) void gemm_nt(
    const bf16* __restrict__ A, const bf16* __restrict__ Bw,
    const float* __restrict__ bias, const float* add, void* out,
    int N, int K)
{
    __shared__ __align__(16) bf16 lA[128 * 32];
    __shared__ __align__(16) bf16 lB[128 * 32];
    const int tid = threadIdx.x;
    const int lane = tid & 63;
    const int wave = tid >> 6;
    const int wm = wave >> 1, wn = wave & 1;
    const int bm = blockIdx.y, bn = blockIdx.x;
    const int quad = lane >> 4;
    const int l16 = lane & 15;

    const char* Ab = (const char*)(A + (size_t)bm * 128 * K);
    const char* Bb = (const char*)(Bw + (size_t)bn * 128 * K);
    const size_t rs = (size_t)K * 2;

    f32x4 acc[4][4] = {};

    for (int k0 = 0; k0 < K; k0 += 32) {
#pragma unroll
        for (int it = 0; it < 2; ++it) {
            int lin = tid * 16 + it * 4096;     // byte offset within 8KB tile
            int row = lin >> 6;                 // 64 B per row (32 bf16)
            int kb = lin & 63;
            async_copy16(Ab + (size_t)row * rs + (size_t)k0 * 2 + kb, (char*)lA + lin);
        }
#pragma unroll
        for (int it = 0; it < 2; ++it) {
            int lin = tid * 16 + it * 4096;
            int row = lin >> 6;
            int kb = lin & 63;
            async_copy16(Bb + (size_t)row * rs + (size_t)k0 * 2 + kb, (char*)lB + lin);
        }
        __syncthreads();
        bf16x8 af[4], bfr[4];
#pragma unroll
        for (int mi = 0; mi < 4; ++mi)
            af[mi] = *(const bf16x8*)(lA + (wm * 64 + mi * 16 + l16) * 32 + quad * 8);
#pragma unroll
        for (int ni = 0; ni < 4; ++ni)
            bfr[ni] = *(const bf16x8*)(lB + (wn * 64 + ni * 16 + l16) * 32 + quad * 8);
#pragma unroll
        for (int mi = 0; mi < 4; ++mi)
#pragma unroll
            for (int ni = 0; ni < 4; ++ni)
                acc[mi][ni] = __builtin_amdgcn_mfma_f32_16x16x32_bf16(
                    af[mi], bfr[ni], acc[mi][ni], 0, 0, 0);
        __syncthreads();
    }

    const int r0 = quad * 4;
#pragma unroll
    for (int mi = 0; mi < 4; ++mi) {
        int growb = bm * 128 + wm * 64 + mi * 16 + r0;
#pragma unroll
        for (int ni = 0; ni < 4; ++ni) {
            int gcol = bn * 128 + wn * 64 + ni * 16 + l16;
            float bcol = bias[gcol];
#pragma unroll
            for (int r = 0; r < 4; ++r) {
                size_t idx = (size_t)(growb + r) * N + gcol;
                float v = acc[mi][ni][r] + bcol;
                if (EPI == 0) {
                    ((bf16*)out)[idx] = __float2bfloat16(v);
                } else if (EPI == 1) {
                    float t = tanhf(0.7978845608f * (v + 0.044715f * v * v * v));
                    ((bf16*)out)[idx] = __float2bfloat16(0.5f * v * (1.f + t));
                } else {
                    ((float*)out)[idx] = v + add[idx];
                }
            }
        }
    }
}

// ---------------- differential attention + subln ----------------
// qkv: [8192, 3456] bf16 (q | k | v). Output attn_bf [8192, 1152] bf16.
// Block: one (b, h, 16-q-row tile). 256 threads.
__global__ __launch_bounds__(256) void attn_kernel(
    const bf16* __restrict__ qkv,
    const float* __restrict__ lq1, const float* __restrict__ lk1,
    const float* __restrict__ lq2, const float* __restrict__ lk2,
    const float* __restrict__ subln_w, bf16* __restrict__ out)
{
    __shared__ __align__(16) bf16 kv[256 * 80];   // K then V, row stride 80 (16B-aligned rows)
    __shared__ float qs[16 * 72];
    __shared__ float wls[16 * 256];

    const int bx = blockIdx.x;
    const int qt = bx & 15;
    const int h = (bx >> 4) & 15;
    const int b = bx >> 8;
    const int tid = threadIdx.x;

    // lambda_full (redundant per thread; tiny, broadcast loads)
    float s1 = 0.f, s2 = 0.f;
    for (int i = 0; i < kHD2; ++i) { s1 += lq1[i] * lk1[i]; s2 += lq2[i] * lk2[i]; }
    const float lam = expf(s1) - expf(s2) + kLambdaInit;

    const size_t tokbase = (size_t)b * kS;

    // load K rows (cols E + h*72 .. +72) as 16B chunks
    for (int c = tid; c < 256 * 9; c += 256) {
        int row = c / 9, seg = c - row * 9;
        *(uint4*)(kv + row * 80 + seg * 8) =
            *(const uint4*)(qkv + (tokbase + row) * kNQKV + kE + h * 72 + seg * 8);
    }
    // load Q tile (16 rows) to fp32
    for (int i = tid; i < 16 * 72; i += 256) {
        int r = i / 72, d = i - r * 72;
        qs[i] = __bfloat162float(qkv[(tokbase + qt * 16 + r) * kNQKV + h * 72 + d]);
    }
    __syncthreads();

    const int r = tid >> 4, jl = tid & 15;
    float se[16], so[16];
    float mxe = -1e30f, mxo = -1e30f;
    const float sc = 0.117851130f;  // 1/sqrt(72)  (scale uses full head_dim)
    const float* qr = qs + r * 72;
    for (int jj = 0; jj < 16; ++jj) {
        int j = jl + jj * 16;
        const bf16* kr = kv + j * 80;
        float ae = 0.f, ao = 0.f;
#pragma unroll 4
        for (int d = 0; d < 36; ++d) {
            ae += qr[d] * __bfloat162float(kr[d]);
            ao += qr[d + 36] * __bfloat162float(kr[d + 36]);
        }
        se[jj] = ae * sc; so[jj] = ao * sc;
        mxe = fmaxf(mxe, se[jj]); mxo = fmaxf(mxo, so[jj]);
    }
    for (int m = 1; m < 16; m <<= 1) {
        mxe = fmaxf(mxe, __shfl_xor(mxe, m, 64));
        mxo = fmaxf(mxo, __shfl_xor(mxo, m, 64));
    }
    float sme = 0.f, smo = 0.f;
    float pe[16], po[16];
    for (int jj = 0; jj < 16; ++jj) {
        pe[jj] = expf(se[jj] - mxe); sme += pe[jj];
        po[jj] = expf(so[jj] - mxo); smo += po[jj];
    }
    for (int m = 1; m < 16; m <<= 1) {
        sme += __shfl_xor(sme, m, 64);
        smo += __shfl_xor(smo, m, 64);
    }
    const float ie = 1.f / sme, io = lam / smo;
    for (int jj = 0; jj < 16; ++jj)
        wls[r * 256 + jl + jj * 16] = pe[jj] * ie - po[jj] * io;
    __syncthreads();

    // overwrite kv with V rows (cols 2E + h*72)
    for (int c = tid; c < 256 * 9; c += 256) {
        int row = c / 9, seg = c - row * 9;
        *(uint4*)(kv + row * 80 + seg * 8) =
            *(const uint4*)(qkv + (tokbase + row) * kNQKV + 2 * kE + h * 72 + seg * 8);
    }
    __syncthreads();

    // P @ V : thread (r, dl) owns dims dl, dl+16, dl+32, dl+48 (+dl+64 if dl<8)
    const int dl = tid & 15;
    const int nd = (dl < 8) ? 5 : 4;
    float acc[5] = {0.f, 0.f, 0.f, 0.f, 0.f};
    const float* wr = wls + r * 256;
#pragma unroll 4
    for (int j = 0; j < 256; ++j) {
        float wv = wr[j];
        const bf16* vr = kv + j * 80;
        acc[0] += wv * __bfloat162float(vr[dl]);
        acc[1] += wv * __bfloat162float(vr[dl + 16]);
        acc[2] += wv * __bfloat162float(vr[dl + 32]);
        acc[3] += wv * __bfloat162float(vr[dl + 48]);
        if (nd == 5) acc[4] += wv * __bfloat162float(vr[dl + 64]);
    }
    // subln RMS over the 72 dims of this row (spread across 16 lanes)
    float ssq = acc[0] * acc[0] + acc[1] * acc[1] + acc[2] * acc[2] + acc[3] * acc[3];
    if (nd == 5) ssq += acc[4] * acc[4];
    for (int m = 1; m < 16; m <<= 1) ssq += __shfl_xor(ssq, m, 64);
    const float scale = rsqrtf(ssq / 72.f + kSublnEps) * (1.f - kLambdaInit);
    const size_t orow = (tokbase + qt * 16 + r) * (size_t)kE + h * 72;
    for (int kk = 0; kk < nd; ++kk) {
        int d = dl + kk * 16;
        out[orow + d] = __float2bfloat16(acc[kk] * scale * subln_w[d]);
    }
}

// ---------------- launch ----------------
extern "C" void kernel_launch(void* const* d_in, const int* in_sizes, int n_in,
                              void* d_out, int out_size, void* d_ws, size_t ws_size,
                              hipStream_t stream)
{
    const float* hidden = (const float*)d_in[0];
    const float* Wq = (const float*)d_in[1];
    const float* bq = (const float*)d_in[2];
    const float* Wk = (const float*)d_in[3];
    const float* bk = (const float*)d_in[4];
    const float* Wv = (const float*)d_in[5];
    const float* bv = (const float*)d_in[6];
    const float* Wo = (const float*)d_in[7];
    const float* bo = (const float*)d_in[8];
    const float* lq1 = (const float*)d_in[9];
    const float* lk1 = (const float*)d_in[10];
    const float* lq2 = (const float*)d_in[11];
    const float* lk2 = (const float*)d_in[12];
    const float* subln_w = (const float*)d_in[13];
    const float* rms1_w = (const float*)d_in[14];
    const float* rms2_w = (const float*)d_in[15];
    const float* fc1_w = (const float*)d_in[16];
    const float* fc1_b = (const float*)d_in[17];
    const float* fc2_w = (const float*)d_in[18];
    const float* fc2_b = (const float*)d_in[19];
    float* outp = (float*)d_out;

    char* wsp = (char*)d_ws;
    size_t off = 0;
    auto alloc = [&](size_t bytes) {
        char* p = wsp + off;
        off += (bytes + 255) & ~(size_t)255;
        return p;
    };
    bf16* wqkv = (bf16*)alloc((size_t)kNQKV * kE * 2);
    bf16* wo   = (bf16*)alloc((size_t)kE * kE * 2);
    bf16* w1   = (bf16*)alloc((size_t)kFFP * kE * 2);
    bf16* w2   = (bf16*)alloc((size_t)kE * kFFP * 2);
    float* bqkv = (float*)alloc((size_t)kNQKV * 4);
    float* b1   = (float*)alloc((size_t)kFFP * 4);
    bf16* xb    = (bf16*)alloc((size_t)kT * kE * 2);     // x1 / attn_out / x2 (sequential reuse)
    bf16* big   = (bf16*)alloc((size_t)kT * kFFP * 2);   // qkv out / fc1 act (sequential reuse)

    int n = kE * kE;
    convert_pad<<<(n + 255) / 256, 256, 0, stream>>>(Wq, wqkv, kE, kE, kE, n);
    convert_pad<<<(n + 255) / 256, 256, 0, stream>>>(Wk, wqkv + n, kE, kE, kE, n);
    convert_pad<<<(n + 255) / 256, 256, 0, stream>>>(Wv, wqkv + 2 * n, kE, kE, kE, n);
    convert_pad<<<(n + 255) / 256, 256, 0, stream>>>(Wo, wo, kE, kE, kE, n);
    n = kFFP * kE;
    convert_pad<<<(n + 255) / 256, 256, 0, stream>>>(fc1_w, w1, kFF, kE, kE, n);
    n = kE * kFFP;
    convert_pad<<<(n + 255) / 256, 256, 0, stream>>>(fc2_w, w2, kE, kFF, kFFP, n);
    prep_bias<<<17, 256, 0, stream>>>(bq, bk, bv, fc1_b, bqkv, b1);

    // x1 = rmsnorm(hidden)
    rmsnorm_kernel<<<kT, 256, 0, stream>>>(hidden, rms1_w, xb, kRmsEps);
    // qkv = x1 @ [Wq;Wk;Wv]^T + b
    gemm_nt<0><<<dim3(kNQKV / 128, kT / 128), 256, 0, stream>>>(
        xb, wqkv, bqkv, nullptr, big, kNQKV, kE);
    // differential attention + subln -> xb
    attn_kernel<<<kB * kH * (kS / 16), 256, 0, stream>>>(
        big, lq1, lk1, lq2, lk2, subln_w, xb);
    // h = attn @ Wo^T + bo + hidden  -> d_out (fp32)
    gemm_nt<2><<<dim3(kE / 128, kT / 128), 256, 0, stream>>>(
        xb, wo, bo, hidden, d_out, kE, kE);
    // x2 = rmsnorm(h)
    rmsnorm_kernel<<<kT, 256, 0, stream>>>(outp, rms2_w, xb, kRmsEps);
    // act = gelu(x2 @ fc1^T + b1)  (N padded to 4352; pad cols exactly 0)
    gemm_nt<1><<<dim3(kFFP / 128, kT / 128), 256, 0, stream>>>(
        xb, w1, b1, nullptr, big, kFFP, kE);
    // out = act @ fc2^T + b2 + h
    gemm_nt<2><<<dim3(kE / 128, kT / 128), 256, 0, stream>>>(
        big, w2, fc2_b, outp, d_out, kE, kFFP);
}

// Round 2
// 793.455 us; speedup vs baseline: 1.8880x; 1.8880x over previous
//
#include <hip/hip_runtime.h>
#include <hip/hip_bf16.h>

typedef __hip_bfloat16 bf16;
typedef __attribute__((ext_vector_type(4))) float f32x4;
typedef __attribute__((ext_vector_type(8))) __bf16 bf16x8;

constexpr int kE   = 1152;
constexpr int kH   = 16;
constexpr int kHD2 = 36;
constexpr int kFF  = 4304;
constexpr int kFFP = 4352;   // padded to 34*128
constexpr int kB   = 32;
constexpr int kS   = 256;
constexpr int kT   = kB * kS;      // 8192 tokens
constexpr int kNQKV = 3 * kE;      // 3456
constexpr float kLambdaInit = 0.7778701f;   // 0.8 - 0.6*exp(-0.3*11)
constexpr float kRmsEps = 1e-6f;
constexpr float kSublnEps = 1e-5f;

__device__ inline void async_copy16(const void* gsrc, void* ldst) {
    __builtin_amdgcn_global_load_lds(
        (__attribute__((address_space(1))) void*)gsrc,
        (__attribute__((address_space(3))) void*)ldst, 16, 0, 0);
}

// ---------------- weight convert / pad ----------------
__global__ __launch_bounds__(256) void convert_pad(
    const float* __restrict__ src, bf16* __restrict__ dst,
    int N, int K, int Kpad, int total)
{
    int i = blockIdx.x * 256 + threadIdx.x;
    if (i >= total) return;
    int n = i / Kpad, k = i - n * Kpad;
    float v = (n < N && k < K) ? src[(size_t)n * K + k] : 0.f;
    dst[i] = __float2bfloat16(v);
}

__global__ __launch_bounds__(256) void prep_bias(
    const float* __restrict__ bq, const float* __restrict__ bk,
    const float* __restrict__ bv, const float* __restrict__ fb,
    float* __restrict__ bqkv, float* __restrict__ fbp)
{
    int i = blockIdx.x * 256 + threadIdx.x;
    if (i < kNQKV) {
        float v = (i < kE) ? bq[i] : (i < 2 * kE) ? bk[i - kE] : bv[i - 2 * kE];
        bqkv[i] = v;
    }
    if (i < kFFP) fbp[i] = (i < kFF) ? fb[i] : 0.f;
}

// ---------------- RMSNorm (fp32 in -> bf16 out) ----------------
__global__ __launch_bounds__(256) void rmsnorm_kernel(
    const float* __restrict__ x, const float* __restrict__ w,
    bf16* __restrict__ out, float eps)
{
    int row = blockIdx.x;
    const float* xr = x + (size_t)row * kE;
    float vals[5];
    float ss = 0.f;
    int n = 0;
    for (int j = threadIdx.x; j < kE; j += 256) {
        float v = xr[j];
        vals[n++] = v;
        ss += v * v;
    }
    for (int m = 32; m > 0; m >>= 1) ss += __shfl_xor(ss, m, 64);
    __shared__ float red[4];
    if ((threadIdx.x & 63) == 0) red[threadIdx.x >> 6] = ss;
    __syncthreads();
    float tot = red[0] + red[1] + red[2] + red[3];
    float scale = rsqrtf(tot / (float)kE + eps);
    n = 0;
    for (int j = threadIdx.x; j < kE; j += 256)
        out[(size_t)row * kE + j] = __float2bfloat16(vals[n++] * scale * w[j]);
}

// ---------------- bf16 NT GEMM, 128x128 tile, BK=32 ----------------
template <int EPI>
__global__ __launch_bounds__(256) void gemm_nt(
    const bf16* __restrict__ A, const bf16* __restrict__ Bw,
    const float* __restrict__ bias, const float* add, void* out,
    int N, int K)
{
    __shared__ __align__(16) bf16 lA[128 * 32];
    __shared__ __align__(16) bf16 lB[128 * 32];
    const int tid = threadIdx.x;
    const int lane = tid & 63;
    const int wave = tid >> 6;
    const int wm = wave >> 1, wn = wave & 1;
    const int bm = blockIdx.y, bn = blockIdx.x;
    const int quad = lane >> 4;
    const int l16 = lane & 15;

    const char* Ab = (const char*)(A + (size_t)bm * 128 * K);
    const char* Bb = (const char*)(Bw + (size_t)bn * 128 * K);
    const size_t rs = (size_t)K * 2;

    f32x4 acc[4][4] = {};

    for (int k0 = 0; k0 < K; k0 += 32) {
#pragma unroll
        for (int it = 0; it < 2; ++it) {
            int lin = tid * 16 + it * 4096;
            int row = lin >> 6;
            int kb = lin & 63;
            async_copy16(Ab + (size_t)row * rs + (size_t)k0 * 2 + kb, (char*)lA + lin);
        }
#pragma unroll
        for (int it = 0; it < 2; ++it) {
            int lin = tid * 16 + it * 4096;
            int row = lin >> 6;
            int kb = lin & 63;
            async_copy16(Bb + (size_t)row * rs + (size_t)k0 * 2 + kb, (char*)lB + lin);
        }
        __syncthreads();
        bf16x8 af[4], bfr[4];
#pragma unroll
        for (int mi = 0; mi < 4; ++mi)
            af[mi] = *(const bf16x8*)(lA + (wm * 64 + mi * 16 + l16) * 32 + quad * 8);
#pragma unroll
        for (int ni = 0; ni < 4; ++ni)
            bfr[ni] = *(const bf16x8*)(lB + (wn * 64 + ni * 16 + l16) * 32 + quad * 8);
#pragma unroll
        for (int mi = 0; mi < 4; ++mi)
#pragma unroll
            for (int ni = 0; ni < 4; ++ni)
                acc[mi][ni] = __builtin_amdgcn_mfma_f32_16x16x32_bf16(
                    af[mi], bfr[ni], acc[mi][ni], 0, 0, 0);
        __syncthreads();
    }

    const int r0 = quad * 4;
#pragma unroll
    for (int mi = 0; mi < 4; ++mi) {
        int growb = bm * 128 + wm * 64 + mi * 16 + r0;
#pragma unroll
        for (int ni = 0; ni < 4; ++ni) {
            int gcol = bn * 128 + wn * 64 + ni * 16 + l16;
            float bcol = bias[gcol];
#pragma unroll
            for (int r = 0; r < 4; ++r) {
                size_t idx = (size_t)(growb + r) * N + gcol;
                float v = acc[mi][ni][r] + bcol;
                if (EPI == 0) {
                    ((bf16*)out)[idx] = __float2bfloat16(v);
                } else if (EPI == 1) {
                    float t = tanhf(0.7978845608f * (v + 0.044715f * v * v * v));
                    ((bf16*)out)[idx] = __float2bfloat16(0.5f * v * (1.f + t));
                } else {
                    ((float*)out)[idx] = v + add[idx];
                }
            }
        }
    }
}

// ---------------- MFMA differential attention + subln ----------------
// One block per (b,h). 4 waves; wave w owns q rows [w*64, w*64+64), in 16-row
// subtiles. K staged in LDS [256][136]: even half dims 0..35 at cols 0..35
// (zeros to 63), odd half dims 36..71 at cols 64..99 (zeros to 127+pad).
// V^T staged [80][264] (d-major) so PV B-frags are contiguous b128 reads.
// Scores (even+odd, 16 k-tiles) live entirely in accumulators; softmax done
// in-register with 16-lane shuffles; P round-trips through per-wave LDS
// buffer (stride 264) into A-fragment layout for PV.
union U8 { bf16x8 v; uint4 u4; uint2 u2[2]; unsigned short e[8]; };

__global__ __launch_bounds__(256) void attn_mfma(
    const bf16* __restrict__ qkv,
    const float* __restrict__ lq1, const float* __restrict__ lk1,
    const float* __restrict__ lq2, const float* __restrict__ lk2,
    const float* __restrict__ subln_w, bf16* __restrict__ out)
{
    __shared__ __align__(16) bf16 Kp[256 * 136];   // 69632 B
    __shared__ __align__(16) bf16 VT[80 * 264];    // 42240 B
    __shared__ __align__(16) bf16 Pb[4 * 16 * 264];// 33792 B   (total 145664)

    const int tid = threadIdx.x;
    const int h = blockIdx.x & 15;
    const int b = blockIdx.x >> 4;
    const size_t tokbase = (size_t)b * kS;

    float s1 = 0.f, s2 = 0.f;
    for (int i = 0; i < kHD2; ++i) { s1 += lq1[i] * lk1[i]; s2 += lq2[i] * lk2[i]; }
    const float lam = __expf(s1) - __expf(s2) + kLambdaInit;

    // ---- stage K (zero-padded halves), 4-elem chunks ----
    for (int c = tid; c < 256 * 34; c += 256) {
        int row = c / 34, s4 = (c - row * 34) * 4;
        uint2 val = make_uint2(0u, 0u);
        const bf16* kg = qkv + (tokbase + row) * kNQKV + kE + h * 72;
        if (s4 < 36)                    val = *(const uint2*)(kg + s4);
        else if (s4 >= 64 && s4 < 100)  val = *(const uint2*)(kg + s4 - 28);
        *(uint2*)(Kp + row * 136 + s4) = val;
    }
    // ---- stage V^T ----
    for (int c = tid; c < 256 * 18; c += 256) {
        int j = c / 18, s4 = (c - j * 18) * 4;
        union { uint2 u; unsigned short e[4]; } uu;
        uu.u = *(const uint2*)(qkv + (tokbase + j) * kNQKV + 2 * kE + h * 72 + s4);
#pragma unroll
        for (int x = 0; x < 4; ++x)
            ((unsigned short*)VT)[(s4 + x) * 264 + j] = uu.e[x];
    }
    for (int c = tid; c < 8 * 256; c += 256) {
        int d = 72 + (c >> 8), j = c & 255;
        ((unsigned short*)VT)[d * 264 + j] = 0;
    }
    __syncthreads();

    const int w = tid >> 6, lane = tid & 63, quad = lane >> 4, l16 = lane & 15;
    bf16* Pw = Pb + w * (16 * 264);
    const float sc = 0.117851130f;            // 1/sqrt(72)
    const float oscale = 1.f - kLambdaInit;

    float sw[5];
#pragma unroll
    for (int dt = 0; dt < 5; ++dt) {
        int d = dt * 16 + l16;
        sw[dt] = (d < 72) ? subln_w[d] : 0.f;
    }

    for (int s = 0; s < 4; ++s) {
        const int q0 = w * 64 + s * 16;
        const bf16* qg = qkv + (tokbase + q0 + l16) * kNQKV + h * 72;
        U8 qe0, qe1, qo0, qo1;
        qe0.u4 = *(const uint4*)(qg + quad * 8);          // dims quad*8..+8 (all real)
        qe1.u4 = *(const uint4*)(qg + 32);                // dims 32..39 (4 real, quad0 only)
        qo0.u2[0] = *(const uint2*)(qg + 36 + quad * 8);  // dims 36+quad*8..+8 (all real)
        qo0.u2[1] = *(const uint2*)(qg + 40 + quad * 8);
        qo1.u2[0] = *(const uint2*)(qg + 68);             // dims 68..75 (4 real, quad0 only)
        qo1.u2[1] = *(const uint2*)(qg + 72);
#pragma unroll
        for (int j = 0; j < 8; ++j) {
            bool keep = (quad == 0) && (j < 4);
            if (!keep) { qe1.e[j] = 0; qo1.e[j] = 0; }
        }

        f32x4 se[16], so[16];
#pragma unroll
        for (int t = 0; t < 16; ++t) { se[t] = f32x4{0,0,0,0}; so[t] = f32x4{0,0,0,0}; }
#pragma unroll
        for (int t = 0; t < 16; ++t) {
            const bf16* kr = Kp + (t * 16 + l16) * 136;
            bf16x8 ke0 = *(const bf16x8*)(kr + quad * 8);
            bf16x8 ke1 = *(const bf16x8*)(kr + 32 + quad * 8);
            bf16x8 ko0 = *(const bf16x8*)(kr + 64 + quad * 8);
            bf16x8 ko1 = *(const bf16x8*)(kr + 96 + quad * 8);
            se[t] = __builtin_amdgcn_mfma_f32_16x16x32_bf16(qe0.v, ke0, se[t], 0, 0, 0);
            se[t] = __builtin_amdgcn_mfma_f32_16x16x32_bf16(qe1.v, ke1, se[t], 0, 0, 0);
            so[t] = __builtin_amdgcn_mfma_f32_16x16x32_bf16(qo0.v, ko0, so[t], 0, 0, 0);
            so[t] = __builtin_amdgcn_mfma_f32_16x16x32_bf16(qo1.v, ko1, so[t], 0, 0, 0);
        }

        // ---- softmax per q-row (row = quad*4+reg; cols t*16+l16) ----
#pragma unroll
        for (int reg = 0; reg < 4; ++reg) {
            float me = -1e30f, mo = -1e30f;
#pragma unroll
            for (int t = 0; t < 16; ++t) {
                me = fmaxf(me, se[t][reg]);
                mo = fmaxf(mo, so[t][reg]);
            }
#pragma unroll
            for (int m = 1; m < 16; m <<= 1) {
                me = fmaxf(me, __shfl_xor(me, m, 64));
                mo = fmaxf(mo, __shfl_xor(mo, m, 64));
            }
            float sume = 0.f, sumo = 0.f;
#pragma unroll
            for (int t = 0; t < 16; ++t) {
                float pe = __expf((se[t][reg] - me) * sc);
                float po = __expf((so[t][reg] - mo) * sc);
                se[t][reg] = pe; sume += pe;
                so[t][reg] = po; sumo += po;
            }
#pragma unroll
            for (int m = 1; m < 16; m <<= 1) {
                sume += __shfl_xor(sume, m, 64);
                sumo += __shfl_xor(sumo, m, 64);
            }
            const float ie = 1.f / sume, io = lam / sumo;
            bf16* prow = Pw + (quad * 4 + reg) * 264;
#pragma unroll
            for (int t = 0; t < 16; ++t) {
                float p = se[t][reg] * ie - so[t][reg] * io;
                prow[t * 16 + l16] = __float2bfloat16(p);
            }
        }

        // ---- P @ V ----
        f32x4 oacc[5];
#pragma unroll
        for (int dt = 0; dt < 5; ++dt) oacc[dt] = f32x4{0,0,0,0};
#pragma unroll
        for (int k0 = 0; k0 < 256; k0 += 32) {
            bf16x8 pf = *(const bf16x8*)(Pw + l16 * 264 + k0 + quad * 8);
#pragma unroll
            for (int dt = 0; dt < 5; ++dt) {
                bf16x8 vf = *(const bf16x8*)(VT + (dt * 16 + l16) * 264 + k0 + quad * 8);
                oacc[dt] = __builtin_amdgcn_mfma_f32_16x16x32_bf16(pf, vf, oacc[dt], 0, 0, 0);
            }
        }

        // ---- subln + store (row = quad*4+reg; d = dt*16+l16) ----
#pragma unroll
        for (int reg = 0; reg < 4; ++reg) {
            float ssq = 0.f;
#pragma unroll
            for (int dt = 0; dt < 5; ++dt) {
                float v = oacc[dt][reg];
                if (dt < 4 || l16 < 8) ssq += v * v;
            }
#pragma unroll
            for (int m = 1; m < 16; m <<= 1) ssq += __shfl_xor(ssq, m, 64);
            float scale = rsqrtf(ssq * (1.f / 72.f) + kSublnEps) * oscale;
            size_t orow = (tokbase + q0 + quad * 4 + reg) * (size_t)kE + h * 72;
#pragma unroll
            for (int dt = 0; dt < 5; ++dt) {
                int d = dt * 16 + l16;
                if (d < 72)
                    out[orow + d] = __float2bfloat16(oacc[dt][reg] * scale * sw[dt]);
            }
        }
    }
}

// ---------------- launch ----------------
extern "C" void kernel_launch(void* const* d_in, const int* in_sizes, int n_in,
                              void* d_out, int out_size, void* d_ws, size_t ws_size,
                              hipStream_t stream)
{
    const float* hidden = (const float*)d_in[0];
    const float* Wq = (const float*)d_in[1];
    const float* bq = (const float*)d_in[2];
    const float* Wk = (const float*)d_in[3];
    const float* bk = (const float*)d_in[4];
    const float* Wv = (const float*)d_in[5];
    const float* bv = (const float*)d_in[6];
    const float* Wo = (const float*)d_in[7];
    const float* bo = (const float*)d_in[8];
    const float* lq1 = (const float*)d_in[9];
    const float* lk1 = (const float*)d_in[10];
    const float* lq2 = (const float*)d_in[11];
    const float* lk2 = (const float*)d_in[12];
    const float* subln_w = (const float*)d_in[13];
    const float* rms1_w = (const float*)d_in[14];
    const float* rms2_w = (const float*)d_in[15];
    const float* fc1_w = (const float*)d_in[16];
    const float* fc1_b = (const float*)d_in[17];
    const float* fc2_w = (const float*)d_in[18];
    const float* fc2_b = (const float*)d_in[19];
    float* outp = (float*)d_out;

    char* wsp = (char*)d_ws;
    size_t off = 0;
    auto alloc = [&](size_t bytes) {
        char* p = wsp + off;
        off += (bytes + 255) & ~(size_t)255;
        return p;
    };
    bf16* wqkv = (bf16*)alloc((size_t)kNQKV * kE * 2);
    bf16* wo   = (bf16*)alloc((size_t)kE * kE * 2);
    bf16* w1   = (bf16*)alloc((size_t)kFFP * kE * 2);
    bf16* w2   = (bf16*)alloc((size_t)kE * kFFP * 2);
    float* bqkv = (float*)alloc((size_t)kNQKV * 4);
    float* b1   = (float*)alloc((size_t)kFFP * 4);
    bf16* xb    = (bf16*)alloc((size_t)kT * kE * 2);
    bf16* big   = (bf16*)alloc((size_t)kT * kFFP * 2);

    int n = kE * kE;
    convert_pad<<<(n + 255) / 256, 256, 0, stream>>>(Wq, wqkv, kE, kE, kE, n);
    convert_pad<<<(n + 255) / 256, 256, 0, stream>>>(Wk, wqkv + n, kE, kE, kE, n);
    convert_pad<<<(n + 255) / 256, 256, 0, stream>>>(Wv, wqkv + 2 * n, kE, kE, kE, n);
    convert_pad<<<(n + 255) / 256, 256, 0, stream>>>(Wo, wo, kE, kE, kE, n);
    n = kFFP * kE;
    convert_pad<<<(n + 255) / 256, 256, 0, stream>>>(fc1_w, w1, kFF, kE, kE, n);
    n = kE * kFFP;
    convert_pad<<<(n + 255) / 256, 256, 0, stream>>>(fc2_w, w2, kE, kFF, kFFP, n);
    prep_bias<<<17, 256, 0, stream>>>(bq, bk, bv, fc1_b, bqkv, b1);

    rmsnorm_kernel<<<kT, 256, 0, stream>>>(hidden, rms1_w, xb, kRmsEps);
    gemm_nt<0><<<dim3(kNQKV / 128, kT / 128), 256, 0, stream>>>(
        xb, wqkv, bqkv, nullptr, big, kNQKV, kE);
    attn_mfma<<<kB * kH, 256, 0, stream>>>(
        big, lq1, lk1, lq2, lk2, subln_w, xb);
    gemm_nt<2><<<dim3(kE / 128, kT / 128), 256, 0, stream>>>(
        xb, wo, bo, hidden, d_out, kE, kE);
    rmsnorm_kernel<<<kT, 256, 0, stream>>>(outp, rms2_w, xb, kRmsEps);
    gemm_nt<1><<<dim3(kFFP / 128, kT / 128), 256, 0, stream>>>(
        xb, w1, b1, nullptr, big, kFFP, kE);
    gemm_nt<2><<<dim3(kE / 128, kT / 128), 256, 0, stream>>>(
        big, w2, fc2_b, outp, d_out, kE, kFFP);
}

// Round 3
// 782.383 us; speedup vs baseline: 1.9147x; 1.0142x over previous
//
#include <hip/hip_runtime.h>
#include <hip/hip_bf16.h>

typedef __hip_bfloat16 bf16;
typedef __attribute__((ext_vector_type(4))) float f32x4;
typedef __attribute__((ext_vector_type(8))) __bf16 bf16x8;

constexpr int kE   = 1152;
constexpr int kH   = 16;
constexpr int kHD2 = 36;
constexpr int kFF  = 4304;
constexpr int kFFP = 4352;   // padded to 34*128
constexpr int kB   = 32;
constexpr int kS   = 256;
constexpr int kT   = kB * kS;      // 8192 tokens
constexpr int kNQKV = 3 * kE;      // 3456
constexpr float kLambdaInit = 0.7778701f;   // 0.8 - 0.6*exp(-0.3*11)
constexpr float kRmsEps = 1e-6f;
constexpr float kSublnEps = 1e-5f;

__device__ inline void async_copy16(const void* gsrc, void* ldst) {
    __builtin_amdgcn_global_load_lds(
        (__attribute__((address_space(1))) void*)gsrc,
        (__attribute__((address_space(3))) void*)ldst, 16, 0, 0);
}

// ---------------- fused weight convert / pad (one launch) ----------------
// wqkv: 3*E*E | wo: E*E | w1: FFP*E (rows padded 4304->4352, K unchanged)
// w2: E*FFP (cols padded 4304->4352)
constexpr int kNEE = kE * kE;                 // 1327104
constexpr int kW1N = kFFP * kE;               // 5013504
constexpr int kW2N = kE * kFFP;               // 5013504
constexpr long kCvtTotal = 4L * kNEE + kW1N + kW2N;   // 15335424

__global__ __launch_bounds__(256) void convert_all(
    const float* __restrict__ Wq, const float* __restrict__ Wk,
    const float* __restrict__ Wv, const float* __restrict__ Wo,
    const float* __restrict__ f1, const float* __restrict__ f2,
    bf16* __restrict__ wqkv, bf16* __restrict__ wo,
    bf16* __restrict__ w1, bf16* __restrict__ w2)
{
    long i = (long)blockIdx.x * 256 + threadIdx.x;
    if (i >= kCvtTotal) return;
    if (i < 3L * kNEE) {
        int j = (int)(i % kNEE);
        const float* src = (i < kNEE) ? Wq : (i < 2L * kNEE) ? Wk : Wv;
        wqkv[i] = __float2bfloat16(src[j]);
    } else if (i < 4L * kNEE) {
        int j = (int)(i - 3L * kNEE);
        wo[j] = __float2bfloat16(Wo[j]);
    } else if (i < 4L * kNEE + kW1N) {
        int j = (int)(i - 4L * kNEE);
        // w1 rows 0..4303 copy (Kpad==K so linear), rows 4304.. are zero
        w1[j] = __float2bfloat16(j < kFF * kE ? f1[j] : 0.f);
    } else {
        int j = (int)(i - 4L * kNEE - kW1N);
        int n = j / kFFP, k = j - n * kFFP;
        w2[j] = __float2bfloat16(k < kFF ? f2[(long)n * kFF + k] : 0.f);
    }
}

__global__ __launch_bounds__(256) void prep_bias(
    const float* __restrict__ bq, const float* __restrict__ bk,
    const float* __restrict__ bv, const float* __restrict__ fb,
    float* __restrict__ bqkv, float* __restrict__ fbp)
{
    int i = blockIdx.x * 256 + threadIdx.x;
    if (i < kNQKV) {
        float v = (i < kE) ? bq[i] : (i < 2 * kE) ? bk[i - kE] : bv[i - 2 * kE];
        bqkv[i] = v;
    }
    if (i < kFFP) fbp[i] = (i < kFF) ? fb[i] : 0.f;
}

// ---------------- RMSNorm (fp32 in -> bf16 out) ----------------
__global__ __launch_bounds__(256) void rmsnorm_kernel(
    const float* __restrict__ x, const float* __restrict__ w,
    bf16* __restrict__ out, float eps)
{
    int row = blockIdx.x;
    const float* xr = x + (size_t)row * kE;
    float vals[5];
    float ss = 0.f;
    int n = 0;
    for (int j = threadIdx.x; j < kE; j += 256) {
        float v = xr[j];
        vals[n++] = v;
        ss += v * v;
    }
    for (int m = 32; m > 0; m >>= 1) ss += __shfl_xor(ss, m, 64);
    __shared__ float red[4];
    if ((threadIdx.x & 63) == 0) red[threadIdx.x >> 6] = ss;
    __syncthreads();
    float tot = red[0] + red[1] + red[2] + red[3];
    float scale = rsqrtf(tot / (float)kE + eps);
    n = 0;
    for (int j = threadIdx.x; j < kE; j += 256)
        out[(size_t)row * kE + j] = __float2bfloat16(vals[n++] * scale * w[j]);
}

// ---------------- bf16 NT GEMM, 128x128 tile, BK=64 (2x[128][32] halves) ----
// A [M,K] bf16 row-major, Bw [N,K] bf16 row-major, C[M,N]. K % 64 == 0.
// EPI: 0 = bf16 out (+bias), 1 = gelu bf16 out (+bias), 2 = fp32 out (+bias+add)
template <int EPI>
__global__ __launch_bounds__(256) void gemm_nt(
    const bf16* __restrict__ A, const bf16* __restrict__ Bw,
    const float* __restrict__ bias, const float* add, void* out,
    int N, int K)
{
    __shared__ __align__(16) bf16 lA[2][128 * 32];
    __shared__ __align__(16) bf16 lB[2][128 * 32];
    const int tid = threadIdx.x;
    const int lane = tid & 63;
    const int wave = tid >> 6;
    const int wm = wave >> 1, wn = wave & 1;
    const int bm = blockIdx.y, bn = blockIdx.x;
    const int quad = lane >> 4;
    const int l16 = lane & 15;

    const char* Ab = (const char*)(A + (size_t)bm * 128 * K);
    const char* Bb = (const char*)(Bw + (size_t)bn * 128 * K);
    const size_t rs = (size_t)K * 2;

    f32x4 acc[4][4] = {};

    const int lin0 = tid * 16;
    const int row0 = lin0 >> 6;          // 2 rows per 16B chunk pattern
    const int kb0 = lin0 & 63;

    for (int k0 = 0; k0 < K; k0 += 64) {
#pragma unroll
        for (int h = 0; h < 2; ++h) {
            const size_t gk = (size_t)(k0 + h * 32) * 2;
#pragma unroll
            for (int it = 0; it < 2; ++it) {
                int lin = lin0 + it * 4096;
                int row = row0 + (it << 6);
                async_copy16(Ab + (size_t)row * rs + gk + kb0,
                             (char*)lA[h] + lin);
            }
#pragma unroll
            for (int it = 0; it < 2; ++it) {
                int lin = lin0 + it * 4096;
                int row = row0 + (it << 6);
                async_copy16(Bb + (size_t)row * rs + gk + kb0,
                             (char*)lB[h] + lin);
            }
        }
        __syncthreads();
#pragma unroll
        for (int h = 0; h < 2; ++h) {
            bf16x8 af[4], bfr[4];
#pragma unroll
            for (int mi = 0; mi < 4; ++mi)
                af[mi] = *(const bf16x8*)(lA[h] + (wm * 64 + mi * 16 + l16) * 32 + quad * 8);
#pragma unroll
            for (int ni = 0; ni < 4; ++ni)
                bfr[ni] = *(const bf16x8*)(lB[h] + (wn * 64 + ni * 16 + l16) * 32 + quad * 8);
#pragma unroll
            for (int mi = 0; mi < 4; ++mi)
#pragma unroll
                for (int ni = 0; ni < 4; ++ni)
                    acc[mi][ni] = __builtin_amdgcn_mfma_f32_16x16x32_bf16(
                        af[mi], bfr[ni], acc[mi][ni], 0, 0, 0);
        }
        __syncthreads();
    }

    const int r0 = quad * 4;
    float bcol[4];
#pragma unroll
    for (int ni = 0; ni < 4; ++ni)
        bcol[ni] = bias[bn * 128 + wn * 64 + ni * 16 + l16];
#pragma unroll
    for (int mi = 0; mi < 4; ++mi) {
        int growb = bm * 128 + wm * 64 + mi * 16 + r0;
#pragma unroll
        for (int ni = 0; ni < 4; ++ni) {
            int gcol = bn * 128 + wn * 64 + ni * 16 + l16;
#pragma unroll
            for (int r = 0; r < 4; ++r) {
                size_t idx = (size_t)(growb + r) * N + gcol;
                float v = acc[mi][ni][r] + bcol[ni];
                if (EPI == 0) {
                    ((bf16*)out)[idx] = __float2bfloat16(v);
                } else if (EPI == 1) {
                    // gelu(v) = v * sigmoid(2*0.79788456*(v+0.044715 v^3))
                    float u = 1.5957691216f * (v + 0.044715f * v * v * v);
                    float g = v / (1.f + __expf(-u));
                    ((bf16*)out)[idx] = __float2bfloat16(g);
                } else {
                    ((float*)out)[idx] = v + add[idx];
                }
            }
        }
    }
}

// ---------------- MFMA differential attention + subln ----------------
union U8 { bf16x8 v; uint4 u4; uint2 u2[2]; unsigned short e[8]; };

__global__ __launch_bounds__(256) void attn_mfma(
    const bf16* __restrict__ qkv,
    const float* __restrict__ lq1, const float* __restrict__ lk1,
    const float* __restrict__ lq2, const float* __restrict__ lk2,
    const float* __restrict__ subln_w, bf16* __restrict__ out)
{
    __shared__ __align__(16) bf16 Kp[256 * 136];   // 69632 B
    __shared__ __align__(16) bf16 VT[80 * 264];    // 42240 B
    __shared__ __align__(16) bf16 Pb[4 * 16 * 264];// 33792 B   (total 145664)

    const int tid = threadIdx.x;
    const int h = blockIdx.x & 15;
    const int b = blockIdx.x >> 4;
    const size_t tokbase = (size_t)b * kS;

    float s1 = 0.f, s2 = 0.f;
    for (int i = 0; i < kHD2; ++i) { s1 += lq1[i] * lk1[i]; s2 += lq2[i] * lk2[i]; }
    const float lam = __expf(s1) - __expf(s2) + kLambdaInit;

    for (int c = tid; c < 256 * 34; c += 256) {
        int row = c / 34, s4 = (c - row * 34) * 4;
        uint2 val = make_uint2(0u, 0u);
        const bf16* kg = qkv + (tokbase + row) * kNQKV + kE + h * 72;
        if (s4 < 36)                    val = *(const uint2*)(kg + s4);
        else if (s4 >= 64 && s4 < 100)  val = *(const uint2*)(kg + s4 - 28);
        *(uint2*)(Kp + row * 136 + s4) = val;
    }
    for (int c = tid; c < 256 * 18; c += 256) {
        int j = c / 18, s4 = (c - j * 18) * 4;
        union { uint2 u; unsigned short e[4]; } uu;
        uu.u = *(const uint2*)(qkv + (tokbase + j) * kNQKV + 2 * kE + h * 72 + s4);
#pragma unroll
        for (int x = 0; x < 4; ++x)
            ((unsigned short*)VT)[(s4 + x) * 264 + j] = uu.e[x];
    }
    for (int c = tid; c < 8 * 256; c += 256) {
        int d = 72 + (c >> 8), j = c & 255;
        ((unsigned short*)VT)[d * 264 + j] = 0;
    }
    __syncthreads();

    const int w = tid >> 6, lane = tid & 63, quad = lane >> 4, l16 = lane & 15;
    bf16* Pw = Pb + w * (16 * 264);
    const float sc = 0.117851130f;            // 1/sqrt(72)
    const float oscale = 1.f - kLambdaInit;

    float sw[5];
#pragma unroll
    for (int dt = 0; dt < 5; ++dt) {
        int d = dt * 16 + l16;
        sw[dt] = (d < 72) ? subln_w[d] : 0.f;
    }

    for (int s = 0; s < 4; ++s) {
        const int q0 = w * 64 + s * 16;
        const bf16* qg = qkv + (tokbase + q0 + l16) * kNQKV + h * 72;
        U8 qe0, qe1, qo0, qo1;
        qe0.u4 = *(const uint4*)(qg + quad * 8);
        qe1.u4 = *(const uint4*)(qg + 32);
        qo0.u2[0] = *(const uint2*)(qg + 36 + quad * 8);
        qo0.u2[1] = *(const uint2*)(qg + 40 + quad * 8);
        qo1.u2[0] = *(const uint2*)(qg + 68);
        qo1.u2[1] = *(const uint2*)(qg + 72);
#pragma unroll
        for (int j = 0; j < 8; ++j) {
            bool keep = (quad == 0) && (j < 4);
            if (!keep) { qe1.e[j] = 0; qo1.e[j] = 0; }
        }

        f32x4 se[16], so[16];
#pragma unroll
        for (int t = 0; t < 16; ++t) { se[t] = f32x4{0,0,0,0}; so[t] = f32x4{0,0,0,0}; }
#pragma unroll
        for (int t = 0; t < 16; ++t) {
            const bf16* kr = Kp + (t * 16 + l16) * 136;
            bf16x8 ke0 = *(const bf16x8*)(kr + quad * 8);
            bf16x8 ke1 = *(const bf16x8*)(kr + 32 + quad * 8);
            bf16x8 ko0 = *(const bf16x8*)(kr + 64 + quad * 8);
            bf16x8 ko1 = *(const bf16x8*)(kr + 96 + quad * 8);
            se[t] = __builtin_amdgcn_mfma_f32_16x16x32_bf16(qe0.v, ke0, se[t], 0, 0, 0);
            se[t] = __builtin_amdgcn_mfma_f32_16x16x32_bf16(qe1.v, ke1, se[t], 0, 0, 0);
            so[t] = __builtin_amdgcn_mfma_f32_16x16x32_bf16(qo0.v, ko0, so[t], 0, 0, 0);
            so[t] = __builtin_amdgcn_mfma_f32_16x16x32_bf16(qo1.v, ko1, so[t], 0, 0, 0);
        }

#pragma unroll
        for (int reg = 0; reg < 4; ++reg) {
            float me = -1e30f, mo = -1e30f;
#pragma unroll
            for (int t = 0; t < 16; ++t) {
                me = fmaxf(me, se[t][reg]);
                mo = fmaxf(mo, so[t][reg]);
            }
#pragma unroll
            for (int m = 1; m < 16; m <<= 1) {
                me = fmaxf(me, __shfl_xor(me, m, 64));
                mo = fmaxf(mo, __shfl_xor(mo, m, 64));
            }
            float sume = 0.f, sumo = 0.f;
#pragma unroll
            for (int t = 0; t < 16; ++t) {
                float pe = __expf((se[t][reg] - me) * sc);
                float po = __expf((so[t][reg] - mo) * sc);
                se[t][reg] = pe; sume += pe;
                so[t][reg] = po; sumo += po;
            }
#pragma unroll
            for (int m = 1; m < 16; m <<= 1) {
                sume += __shfl_xor(sume, m, 64);
                sumo += __shfl_xor(sumo, m, 64);
            }
            const float ie = 1.f / sume, io = lam / sumo;
            bf16* prow = Pw + (quad * 4 + reg) * 264;
#pragma unroll
            for (int t = 0; t < 16; ++t) {
                float p = se[t][reg] * ie - so[t][reg] * io;
                prow[t * 16 + l16] = __float2bfloat16(p);
            }
        }

        f32x4 oacc[5];
#pragma unroll
        for (int dt = 0; dt < 5; ++dt) oacc[dt] = f32x4{0,0,0,0};
#pragma unroll
        for (int k0 = 0; k0 < 256; k0 += 32) {
            bf16x8 pf = *(const bf16x8*)(Pw + l16 * 264 + k0 + quad * 8);
#pragma unroll
            for (int dt = 0; dt < 5; ++dt) {
                bf16x8 vf = *(const bf16x8*)(VT + (dt * 16 + l16) * 264 + k0 + quad * 8);
                oacc[dt] = __builtin_amdgcn_mfma_f32_16x16x32_bf16(pf, vf, oacc[dt], 0, 0, 0);
            }
        }

#pragma unroll
        for (int reg = 0; reg < 4; ++reg) {
            float ssq = 0.f;
#pragma unroll
            for (int dt = 0; dt < 5; ++dt) {
                float v = oacc[dt][reg];
                if (dt < 4 || l16 < 8) ssq += v * v;
            }
#pragma unroll
            for (int m = 1; m < 16; m <<= 1) ssq += __shfl_xor(ssq, m, 64);
            float scale = rsqrtf(ssq * (1.f / 72.f) + kSublnEps) * oscale;
            size_t orow = (tokbase + q0 + quad * 4 + reg) * (size_t)kE + h * 72;
#pragma unroll
            for (int dt = 0; dt < 5; ++dt) {
                int d = dt * 16 + l16;
                if (d < 72)
                    out[orow + d] = __float2bfloat16(oacc[dt][reg] * scale * sw[dt]);
            }
        }
    }
}

// ---------------- launch ----------------
extern "C" void kernel_launch(void* const* d_in, const int* in_sizes, int n_in,
                              void* d_out, int out_size, void* d_ws, size_t ws_size,
                              hipStream_t stream)
{
    const float* hidden = (const float*)d_in[0];
    const float* Wq = (const float*)d_in[1];
    const float* bq = (const float*)d_in[2];
    const float* Wk = (const float*)d_in[3];
    const float* bk = (const float*)d_in[4];
    const float* Wv = (const float*)d_in[5];
    const float* bv = (const float*)d_in[6];
    const float* Wo = (const float*)d_in[7];
    const float* bo = (const float*)d_in[8];
    const float* lq1 = (const float*)d_in[9];
    const float* lk1 = (const float*)d_in[10];
    const float* lq2 = (const float*)d_in[11];
    const float* lk2 = (const float*)d_in[12];
    const float* subln_w = (const float*)d_in[13];
    const float* rms1_w = (const float*)d_in[14];
    const float* rms2_w = (const float*)d_in[15];
    const float* fc1_w = (const float*)d_in[16];
    const float* fc1_b = (const float*)d_in[17];
    const float* fc2_w = (const float*)d_in[18];
    const float* fc2_b = (const float*)d_in[19];
    float* outp = (float*)d_out;

    char* wsp = (char*)d_ws;
    size_t off = 0;
    auto alloc = [&](size_t bytes) {
        char* p = wsp + off;
        off += (bytes + 255) & ~(size_t)255;
        return p;
    };
    bf16* wqkv = (bf16*)alloc((size_t)kNQKV * kE * 2);
    bf16* wo   = (bf16*)alloc((size_t)kE * kE * 2);
    bf16* w1   = (bf16*)alloc((size_t)kFFP * kE * 2);
    bf16* w2   = (bf16*)alloc((size_t)kE * kFFP * 2);
    float* bqkv = (float*)alloc((size_t)kNQKV * 4);
    float* b1   = (float*)alloc((size_t)kFFP * 4);
    bf16* xb    = (bf16*)alloc((size_t)kT * kE * 2);
    bf16* big   = (bf16*)alloc((size_t)kT * kFFP * 2);

    convert_all<<<(int)((kCvtTotal + 255) / 256), 256, 0, stream>>>(
        Wq, Wk, Wv, Wo, fc1_w, fc2_w, wqkv, wo, w1, w2);
    prep_bias<<<17, 256, 0, stream>>>(bq, bk, bv, fc1_b, bqkv, b1);

    rmsnorm_kernel<<<kT, 256, 0, stream>>>(hidden, rms1_w, xb, kRmsEps);
    gemm_nt<0><<<dim3(kNQKV / 128, kT / 128), 256, 0, stream>>>(
        xb, wqkv, bqkv, nullptr, big, kNQKV, kE);
    attn_mfma<<<kB * kH, 256, 0, stream>>>(
        big, lq1, lk1, lq2, lk2, subln_w, xb);
    gemm_nt<2><<<dim3(kE / 128, kT / 128), 256, 0, stream>>>(
        xb, wo, bo, hidden, d_out, kE, kE);
    rmsnorm_kernel<<<kT, 256, 0, stream>>>(outp, rms2_w, xb, kRmsEps);
    gemm_nt<1><<<dim3(kFFP / 128, kT / 128), 256, 0, stream>>>(
        xb, w1, b1, nullptr, big, kFFP, kE);
    gemm_nt<2><<<dim3(kE / 128, kT / 128), 256, 0, stream>>>(
        big, w2, fc2_b, outp, d_out, kE, kFFP);
}

// Round 4
// 776.727 us; speedup vs baseline: 1.9287x; 1.0073x over previous
//
#include <hip/hip_runtime.h>
#include <hip/hip_bf16.h>

typedef __hip_bfloat16 bf16;
typedef __attribute__((ext_vector_type(4))) float f32x4;
typedef __attribute__((ext_vector_type(8))) __bf16 bf16x8;

constexpr int kE   = 1152;
constexpr int kH   = 16;
constexpr int kHD2 = 36;
constexpr int kFF  = 4304;
constexpr int kFFP = 4352;   // padded to 34*128
constexpr int kB   = 32;
constexpr int kS   = 256;
constexpr int kT   = kB * kS;      // 8192 tokens
constexpr int kNQKV = 3 * kE;      // 3456
constexpr float kLambdaInit = 0.7778701f;   // 0.8 - 0.6*exp(-0.3*11)
constexpr float kRmsEps = 1e-6f;
constexpr float kSublnEps = 1e-5f;

__device__ inline void async_copy16(const void* gsrc, void* ldst) {
    __builtin_amdgcn_global_load_lds(
        (__attribute__((address_space(1))) void*)gsrc,
        (__attribute__((address_space(3))) void*)ldst, 16, 0, 0);
}

// ---------------- fused weight convert / pad (one launch) ----------------
constexpr int kNEE = kE * kE;                 // 1327104
constexpr int kW1N = kFFP * kE;               // 5013504
constexpr int kW2N = kE * kFFP;               // 5013504
constexpr long kCvtTotal = 4L * kNEE + kW1N + kW2N;   // 15335424

__global__ __launch_bounds__(256) void convert_all(
    const float* __restrict__ Wq, const float* __restrict__ Wk,
    const float* __restrict__ Wv, const float* __restrict__ Wo,
    const float* __restrict__ f1, const float* __restrict__ f2,
    bf16* __restrict__ wqkv, bf16* __restrict__ wo,
    bf16* __restrict__ w1, bf16* __restrict__ w2)
{
    long i = (long)blockIdx.x * 256 + threadIdx.x;
    if (i >= kCvtTotal) return;
    if (i < 3L * kNEE) {
        int j = (int)(i % kNEE);
        const float* src = (i < kNEE) ? Wq : (i < 2L * kNEE) ? Wk : Wv;
        wqkv[i] = __float2bfloat16(src[j]);
    } else if (i < 4L * kNEE) {
        int j = (int)(i - 3L * kNEE);
        wo[j] = __float2bfloat16(Wo[j]);
    } else if (i < 4L * kNEE + kW1N) {
        int j = (int)(i - 4L * kNEE);
        w1[j] = __float2bfloat16(j < kFF * kE ? f1[j] : 0.f);
    } else {
        int j = (int)(i - 4L * kNEE - kW1N);
        int n = j / kFFP, k = j - n * kFFP;
        w2[j] = __float2bfloat16(k < kFF ? f2[(long)n * kFF + k] : 0.f);
    }
}

__global__ __launch_bounds__(256) void prep_bias(
    const float* __restrict__ bq, const float* __restrict__ bk,
    const float* __restrict__ bv, const float* __restrict__ fb,
    float* __restrict__ bqkv, float* __restrict__ fbp)
{
    int i = blockIdx.x * 256 + threadIdx.x;
    if (i < kNQKV) {
        float v = (i < kE) ? bq[i] : (i < 2 * kE) ? bk[i - kE] : bv[i - 2 * kE];
        bqkv[i] = v;
    }
    if (i < kFFP) fbp[i] = (i < kFF) ? fb[i] : 0.f;
}

// ---------------- RMSNorm (fp32 in -> bf16 out) ----------------
__global__ __launch_bounds__(256) void rmsnorm_kernel(
    const float* __restrict__ x, const float* __restrict__ w,
    bf16* __restrict__ out, float eps)
{
    int row = blockIdx.x;
    const float* xr = x + (size_t)row * kE;
    float vals[5];
    float ss = 0.f;
    int n = 0;
    for (int j = threadIdx.x; j < kE; j += 256) {
        float v = xr[j];
        vals[n++] = v;
        ss += v * v;
    }
    for (int m = 32; m > 0; m >>= 1) ss += __shfl_xor(ss, m, 64);
    __shared__ float red[4];
    if ((threadIdx.x & 63) == 0) red[threadIdx.x >> 6] = ss;
    __syncthreads();
    float tot = red[0] + red[1] + red[2] + red[3];
    float scale = rsqrtf(tot / (float)kE + eps);
    n = 0;
    for (int j = threadIdx.x; j < kE; j += 256)
        out[(size_t)row * kE + j] = __float2bfloat16(vals[n++] * scale * w[j]);
}

// ---------------- bf16 NT GEMM, 128x128 tile, BK=64 (2x[128][32] halves) ----
// EPI: 0 = bf16 out (+bias), 1 = gelu bf16 out (+bias), 2 = fp32 out (+bias+add)
template <int EPI>
__global__ __launch_bounds__(256) void gemm_nt(
    const bf16* __restrict__ A, const bf16* __restrict__ Bw,
    const float* __restrict__ bias, const float* add, void* out,
    int N, int K)
{
    __shared__ __align__(16) bf16 lA[2][128 * 32];
    __shared__ __align__(16) bf16 lB[2][128 * 32];
    const int tid = threadIdx.x;
    const int lane = tid & 63;
    const int wave = tid >> 6;
    const int wm = wave >> 1, wn = wave & 1;
    const int bm = blockIdx.y, bn = blockIdx.x;
    const int quad = lane >> 4;
    const int l16 = lane & 15;

    const char* Ab = (const char*)(A + (size_t)bm * 128 * K);
    const char* Bb = (const char*)(Bw + (size_t)bn * 128 * K);
    const size_t rs = (size_t)K * 2;

    f32x4 acc[4][4] = {};

    const int lin0 = tid * 16;
    const int row0 = lin0 >> 6;
    const int kb0 = lin0 & 63;

    for (int k0 = 0; k0 < K; k0 += 64) {
#pragma unroll
        for (int h = 0; h < 2; ++h) {
            const size_t gk = (size_t)(k0 + h * 32) * 2;
#pragma unroll
            for (int it = 0; it < 2; ++it) {
                int lin = lin0 + it * 4096;
                int row = row0 + (it << 6);
                async_copy16(Ab + (size_t)row * rs + gk + kb0,
                             (char*)lA[h] + lin);
            }
#pragma unroll
            for (int it = 0; it < 2; ++it) {
                int lin = lin0 + it * 4096;
                int row = row0 + (it << 6);
                async_copy16(Bb + (size_t)row * rs + gk + kb0,
                             (char*)lB[h] + lin);
            }
        }
        __syncthreads();
#pragma unroll
        for (int h = 0; h < 2; ++h) {
            bf16x8 af[4], bfr[4];
#pragma unroll
            for (int mi = 0; mi < 4; ++mi)
                af[mi] = *(const bf16x8*)(lA[h] + (wm * 64 + mi * 16 + l16) * 32 + quad * 8);
#pragma unroll
            for (int ni = 0; ni < 4; ++ni)
                bfr[ni] = *(const bf16x8*)(lB[h] + (wn * 64 + ni * 16 + l16) * 32 + quad * 8);
#pragma unroll
            for (int mi = 0; mi < 4; ++mi)
#pragma unroll
                for (int ni = 0; ni < 4; ++ni)
                    acc[mi][ni] = __builtin_amdgcn_mfma_f32_16x16x32_bf16(
                        af[mi], bfr[ni], acc[mi][ni], 0, 0, 0);
        }
        __syncthreads();
    }

    const int r0 = quad * 4;
    float bcol[4];
#pragma unroll
    for (int ni = 0; ni < 4; ++ni)
        bcol[ni] = bias[bn * 128 + wn * 64 + ni * 16 + l16];
#pragma unroll
    for (int mi = 0; mi < 4; ++mi) {
        int growb = bm * 128 + wm * 64 + mi * 16 + r0;
#pragma unroll
        for (int ni = 0; ni < 4; ++ni) {
            int gcol = bn * 128 + wn * 64 + ni * 16 + l16;
#pragma unroll
            for (int r = 0; r < 4; ++r) {
                size_t idx = (size_t)(growb + r) * N + gcol;
                float v = acc[mi][ni][r] + bcol[ni];
                if (EPI == 0) {
                    ((bf16*)out)[idx] = __float2bfloat16(v);
                } else if (EPI == 1) {
                    float u = 1.5957691216f * (v + 0.044715f * v * v * v);
                    float g = v / (1.f + __expf(-u));
                    ((bf16*)out)[idx] = __float2bfloat16(g);
                } else {
                    ((float*)out)[idx] = v + add[idx];
                }
            }
        }
    }
}

// ---------------- bf16 NT GEMM, 64x128 tile, BK=64 — for small-N GEMMs ----
// Doubles grid size (grid-starved o-proj / fc2). fp32 out = acc + bias + add.
__global__ __launch_bounds__(256) void gemm_nt64(
    const bf16* __restrict__ A, const bf16* __restrict__ Bw,
    const float* __restrict__ bias, const float* __restrict__ add,
    float* __restrict__ out, int N, int K)
{
    __shared__ __align__(16) bf16 lA[2][64 * 32];
    __shared__ __align__(16) bf16 lB[2][128 * 32];
    const int tid = threadIdx.x;
    const int lane = tid & 63;
    const int wave = tid >> 6;
    const int wm = wave >> 1, wn = wave & 1;   // wave-grid 2x2: 32 rows x 64 cols each
    const int bm = blockIdx.y, bn = blockIdx.x;
    const int quad = lane >> 4;
    const int l16 = lane & 15;

    const char* Ab = (const char*)(A + (size_t)bm * 64 * K);
    const char* Bb = (const char*)(Bw + (size_t)bn * 128 * K);
    const size_t rs = (size_t)K * 2;

    f32x4 acc[2][4] = {};

    const int lin0 = tid * 16;
    const int row0 = lin0 >> 6;          // tid/4, 0..63
    const int kb0 = lin0 & 63;

    for (int k0 = 0; k0 < K; k0 += 64) {
#pragma unroll
        for (int h = 0; h < 2; ++h) {
            const size_t gk = (size_t)(k0 + h * 32) * 2;
            // A half-tile: 64 rows x 32 k = 4096 B = one 16B chunk/thread
            async_copy16(Ab + (size_t)row0 * rs + gk + kb0, (char*)lA[h] + lin0);
            // B half-tile: 128 rows = two chunks/thread
#pragma unroll
            for (int it = 0; it < 2; ++it) {
                int lin = lin0 + it * 4096;
                int row = row0 + (it << 6);
                async_copy16(Bb + (size_t)row * rs + gk + kb0, (char*)lB[h] + lin);
            }
        }
        __syncthreads();
#pragma unroll
        for (int h = 0; h < 2; ++h) {
            bf16x8 af[2], bfr[4];
#pragma unroll
            for (int mi = 0; mi < 2; ++mi)
                af[mi] = *(const bf16x8*)(lA[h] + (wm * 32 + mi * 16 + l16) * 32 + quad * 8);
#pragma unroll
            for (int ni = 0; ni < 4; ++ni)
                bfr[ni] = *(const bf16x8*)(lB[h] + (wn * 64 + ni * 16 + l16) * 32 + quad * 8);
#pragma unroll
            for (int mi = 0; mi < 2; ++mi)
#pragma unroll
                for (int ni = 0; ni < 4; ++ni)
                    acc[mi][ni] = __builtin_amdgcn_mfma_f32_16x16x32_bf16(
                        af[mi], bfr[ni], acc[mi][ni], 0, 0, 0);
        }
        __syncthreads();
    }

    float bcol[4];
#pragma unroll
    for (int ni = 0; ni < 4; ++ni)
        bcol[ni] = bias[bn * 128 + wn * 64 + ni * 16 + l16];
#pragma unroll
    for (int mi = 0; mi < 2; ++mi) {
        int growb = bm * 64 + wm * 32 + mi * 16 + quad * 4;
#pragma unroll
        for (int ni = 0; ni < 4; ++ni) {
            int gcol = bn * 128 + wn * 64 + ni * 16 + l16;
#pragma unroll
            for (int r = 0; r < 4; ++r) {
                size_t idx = (size_t)(growb + r) * N + gcol;
                out[idx] = acc[mi][ni][r] + bcol[ni] + add[idx];
            }
        }
    }
}

// ---------------- MFMA differential attention + subln ----------------
union U8 { bf16x8 v; uint4 u4; uint2 u2[2]; unsigned short e[8]; };

__global__ __launch_bounds__(256) void attn_mfma(
    const bf16* __restrict__ qkv,
    const float* __restrict__ lq1, const float* __restrict__ lk1,
    const float* __restrict__ lq2, const float* __restrict__ lk2,
    const float* __restrict__ subln_w, bf16* __restrict__ out)
{
    __shared__ __align__(16) bf16 Kp[256 * 136];   // 69632 B
    __shared__ __align__(16) bf16 VT[80 * 264];    // 42240 B
    __shared__ __align__(16) bf16 Pb[4 * 16 * 264];// 33792 B   (total 145664)

    const int tid = threadIdx.x;
    const int h = blockIdx.x & 15;
    const int b = blockIdx.x >> 4;
    const size_t tokbase = (size_t)b * kS;

    float s1 = 0.f, s2 = 0.f;
    for (int i = 0; i < kHD2; ++i) { s1 += lq1[i] * lk1[i]; s2 += lq2[i] * lk2[i]; }
    const float lam = __expf(s1) - __expf(s2) + kLambdaInit;

    for (int c = tid; c < 256 * 34; c += 256) {
        int row = c / 34, s4 = (c - row * 34) * 4;
        uint2 val = make_uint2(0u, 0u);
        const bf16* kg = qkv + (tokbase + row) * kNQKV + kE + h * 72;
        if (s4 < 36)                    val = *(const uint2*)(kg + s4);
        else if (s4 >= 64 && s4 < 100)  val = *(const uint2*)(kg + s4 - 28);
        *(uint2*)(Kp + row * 136 + s4) = val;
    }
    for (int c = tid; c < 256 * 18; c += 256) {
        int j = c / 18, s4 = (c - j * 18) * 4;
        union { uint2 u; unsigned short e[4]; } uu;
        uu.u = *(const uint2*)(qkv + (tokbase + j) * kNQKV + 2 * kE + h * 72 + s4);
#pragma unroll
        for (int x = 0; x < 4; ++x)
            ((unsigned short*)VT)[(s4 + x) * 264 + j] = uu.e[x];
    }
    for (int c = tid; c < 8 * 256; c += 256) {
        int d = 72 + (c >> 8), j = c & 255;
        ((unsigned short*)VT)[d * 264 + j] = 0;
    }
    __syncthreads();

    const int w = tid >> 6, lane = tid & 63, quad = lane >> 4, l16 = lane & 15;
    bf16* Pw = Pb + w * (16 * 264);
    const float sc = 0.117851130f;            // 1/sqrt(72)
    const float oscale = 1.f - kLambdaInit;

    float sw[5];
#pragma unroll
    for (int dt = 0; dt < 5; ++dt) {
        int d = dt * 16 + l16;
        sw[dt] = (d < 72) ? subln_w[d] : 0.f;
    }

    for (int s = 0; s < 4; ++s) {
        const int q0 = w * 64 + s * 16;
        const bf16* qg = qkv + (tokbase + q0 + l16) * kNQKV + h * 72;
        U8 qe0, qe1, qo0, qo1;
        qe0.u4 = *(const uint4*)(qg + quad * 8);
        qe1.u4 = *(const uint4*)(qg + 32);
        qo0.u2[0] = *(const uint2*)(qg + 36 + quad * 8);
        qo0.u2[1] = *(const uint2*)(qg + 40 + quad * 8);
        qo1.u2[0] = *(const uint2*)(qg + 68);
        qo1.u2[1] = *(const uint2*)(qg + 72);
#pragma unroll
        for (int j = 0; j < 8; ++j) {
            bool keep = (quad == 0) && (j < 4);
            if (!keep) { qe1.e[j] = 0; qo1.e[j] = 0; }
        }

        f32x4 se[16], so[16];
#pragma unroll
        for (int t = 0; t < 16; ++t) { se[t] = f32x4{0,0,0,0}; so[t] = f32x4{0,0,0,0}; }
#pragma unroll
        for (int t = 0; t < 16; ++t) {
            const bf16* kr = Kp + (t * 16 + l16) * 136;
            bf16x8 ke0 = *(const bf16x8*)(kr + quad * 8);
            bf16x8 ke1 = *(const bf16x8*)(kr + 32 + quad * 8);
            bf16x8 ko0 = *(const bf16x8*)(kr + 64 + quad * 8);
            bf16x8 ko1 = *(const bf16x8*)(kr + 96 + quad * 8);
            se[t] = __builtin_amdgcn_mfma_f32_16x16x32_bf16(qe0.v, ke0, se[t], 0, 0, 0);
            se[t] = __builtin_amdgcn_mfma_f32_16x16x32_bf16(qe1.v, ke1, se[t], 0, 0, 0);
            so[t] = __builtin_amdgcn_mfma_f32_16x16x32_bf16(qo0.v, ko0, so[t], 0, 0, 0);
            so[t] = __builtin_amdgcn_mfma_f32_16x16x32_bf16(qo1.v, ko1, so[t], 0, 0, 0);
        }

#pragma unroll
        for (int reg = 0; reg < 4; ++reg) {
            float me = -1e30f, mo = -1e30f;
#pragma unroll
            for (int t = 0; t < 16; ++t) {
                me = fmaxf(me, se[t][reg]);
                mo = fmaxf(mo, so[t][reg]);
            }
#pragma unroll
            for (int m = 1; m < 16; m <<= 1) {
                me = fmaxf(me, __shfl_xor(me, m, 64));
                mo = fmaxf(mo, __shfl_xor(mo, m, 64));
            }
            float sume = 0.f, sumo = 0.f;
#pragma unroll
            for (int t = 0; t < 16; ++t) {
                float pe = __expf((se[t][reg] - me) * sc);
                float po = __expf((so[t][reg] - mo) * sc);
                se[t][reg] = pe; sume += pe;
                so[t][reg] = po; sumo += po;
            }
#pragma unroll
            for (int m = 1; m < 16; m <<= 1) {
                sume += __shfl_xor(sume, m, 64);
                sumo += __shfl_xor(sumo, m, 64);
            }
            const float ie = 1.f / sume, io = lam / sumo;
            bf16* prow = Pw + (quad * 4 + reg) * 264;
#pragma unroll
            for (int t = 0; t < 16; ++t) {
                float p = se[t][reg] * ie - so[t][reg] * io;
                prow[t * 16 + l16] = __float2bfloat16(p);
            }
        }

        f32x4 oacc[5];
#pragma unroll
        for (int dt = 0; dt < 5; ++dt) oacc[dt] = f32x4{0,0,0,0};
#pragma unroll
        for (int k0 = 0; k0 < 256; k0 += 32) {
            bf16x8 pf = *(const bf16x8*)(Pw + l16 * 264 + k0 + quad * 8);
#pragma unroll
            for (int dt = 0; dt < 5; ++dt) {
                bf16x8 vf = *(const bf16x8*)(VT + (dt * 16 + l16) * 264 + k0 + quad * 8);
                oacc[dt] = __builtin_amdgcn_mfma_f32_16x16x32_bf16(pf, vf, oacc[dt], 0, 0, 0);
            }
        }

#pragma unroll
        for (int reg = 0; reg < 4; ++reg) {
            float ssq = 0.f;
#pragma unroll
            for (int dt = 0; dt < 5; ++dt) {
                float v = oacc[dt][reg];
                if (dt < 4 || l16 < 8) ssq += v * v;
            }
#pragma unroll
            for (int m = 1; m < 16; m <<= 1) ssq += __shfl_xor(ssq, m, 64);
            float scale = rsqrtf(ssq * (1.f / 72.f) + kSublnEps) * oscale;
            size_t orow = (tokbase + q0 + quad * 4 + reg) * (size_t)kE + h * 72;
#pragma unroll
            for (int dt = 0; dt < 5; ++dt) {
                int d = dt * 16 + l16;
                if (d < 72)
                    out[orow + d] = __float2bfloat16(oacc[dt][reg] * scale * sw[dt]);
            }
        }
    }
}

// ---------------- launch ----------------
extern "C" void kernel_launch(void* const* d_in, const int* in_sizes, int n_in,
                              void* d_out, int out_size, void* d_ws, size_t ws_size,
                              hipStream_t stream)
{
    const float* hidden = (const float*)d_in[0];
    const float* Wq = (const float*)d_in[1];
    const float* bq = (const float*)d_in[2];
    const float* Wk = (const float*)d_in[3];
    const float* bk = (const float*)d_in[4];
    const float* Wv = (const float*)d_in[5];
    const float* bv = (const float*)d_in[6];
    const float* Wo = (const float*)d_in[7];
    const float* bo = (const float*)d_in[8];
    const float* lq1 = (const float*)d_in[9];
    const float* lk1 = (const float*)d_in[10];
    const float* lq2 = (const float*)d_in[11];
    const float* lk2 = (const float*)d_in[12];
    const float* subln_w = (const float*)d_in[13];
    const float* rms1_w = (const float*)d_in[14];
    const float* rms2_w = (const float*)d_in[15];
    const float* fc1_w = (const float*)d_in[16];
    const float* fc1_b = (const float*)d_in[17];
    const float* fc2_w = (const float*)d_in[18];
    const float* fc2_b = (const float*)d_in[19];
    float* outp = (float*)d_out;

    char* wsp = (char*)d_ws;
    size_t off = 0;
    auto alloc = [&](size_t bytes) {
        char* p = wsp + off;
        off += (bytes + 255) & ~(size_t)255;
        return p;
    };
    bf16* wqkv = (bf16*)alloc((size_t)kNQKV * kE * 2);
    bf16* wo   = (bf16*)alloc((size_t)kE * kE * 2);
    bf16* w1   = (bf16*)alloc((size_t)kFFP * kE * 2);
    bf16* w2   = (bf16*)alloc((size_t)kE * kFFP * 2);
    float* bqkv = (float*)alloc((size_t)kNQKV * 4);
    float* b1   = (float*)alloc((size_t)kFFP * 4);
    bf16* xb    = (bf16*)alloc((size_t)kT * kE * 2);
    bf16* big   = (bf16*)alloc((size_t)kT * kFFP * 2);

    convert_all<<<(int)((kCvtTotal + 255) / 256), 256, 0, stream>>>(
        Wq, Wk, Wv, Wo, fc1_w, fc2_w, wqkv, wo, w1, w2);
    prep_bias<<<17, 256, 0, stream>>>(bq, bk, bv, fc1_b, bqkv, b1);

    rmsnorm_kernel<<<kT, 256, 0, stream>>>(hidden, rms1_w, xb, kRmsEps);
    gemm_nt<0><<<dim3(kNQKV / 128, kT / 128), 256, 0, stream>>>(
        xb, wqkv, bqkv, nullptr, big, kNQKV, kE);
    attn_mfma<<<kB * kH, 256, 0, stream>>>(
        big, lq1, lk1, lq2, lk2, subln_w, xb);
    // h = attn @ Wo^T + bo + hidden -> d_out (fp32); 64-row tiles => 1152 blocks
    gemm_nt64<<<dim3(kE / 128, kT / 64), 256, 0, stream>>>(
        xb, wo, bo, hidden, (float*)d_out, kE, kE);
    rmsnorm_kernel<<<kT, 256, 0, stream>>>(outp, rms2_w, xb, kRmsEps);
    gemm_nt<1><<<dim3(kFFP / 128, kT / 128), 256, 0, stream>>>(
        xb, w1, b1, nullptr, big, kFFP, kE);
    // out = act @ fc2^T + b2 + h; 64-row tiles => 1152 blocks
    gemm_nt64<<<dim3(kE / 128, kT / 64), 256, 0, stream>>>(
        big, w2, fc2_b, outp, (float*)d_out, kE, kFFP);
}